// Round 1
// baseline (27.812 us; speedup 1.0000x reference)
//
#include <hip/hip_runtime.h>

typedef unsigned int u32;
typedef unsigned long long u64;

#define NEXP 64
#define CHUNK 1024
#define WPB 4                  // waves (chunks) per block
#define ROUNDS (CHUNK / 64)    // 16

// ---------------- K1: per-chunk histogram ----------------
// hist layout: hist[c * 64 + e]  (chunk-major)
__global__ void k_hist(const int* __restrict__ experts, u32* __restrict__ hist) {
    __shared__ u32 h[WPB][NEXP];
    const int tid  = threadIdx.x;
    const int wv   = tid >> 6;
    const int lane = tid & 63;
    h[wv][lane] = 0;
    __syncthreads();
    const int c = blockIdx.x * WPB + wv;
    const int4* p = (const int4*)(experts + (size_t)c * CHUNK);
#pragma unroll
    for (int r = 0; r < CHUNK / 256; ++r) {
        int4 v = p[r * 64 + lane];
        atomicAdd(&h[wv][v.x], 1u);
        atomicAdd(&h[wv][v.y], 1u);
        atomicAdd(&h[wv][v.z], 1u);
        atomicAdd(&h[wv][v.w], 1u);
    }
    __syncthreads();
    hist[(size_t)c * NEXP + lane] = h[wv][lane];
}

// ---------------- K2: per-expert exclusive scan over chunks (in place) ----
// grid = 64 blocks (one per expert), block = NCHUNK threads (1024)
__global__ void k_scan_chunks(u32* __restrict__ hist, u32* __restrict__ totals,
                              int nchunk) {
    const int e = blockIdx.x;
    const int t = threadIdx.x;           // chunk id
    const int lane = t & 63, wv = t >> 6;
    u32 v = hist[(size_t)t * NEXP + e];
    // wave inclusive scan
    u32 x = v;
#pragma unroll
    for (int d = 1; d < 64; d <<= 1) {
        u32 y = __shfl_up(x, d);
        if (lane >= d) x += y;
    }
    __shared__ u32 wsum[16];
    if (lane == 63) wsum[wv] = x;
    __syncthreads();
    if (t < 16) {
        u32 y = wsum[t];
#pragma unroll
        for (int d = 1; d < 16; d <<= 1) {
            u32 z = __shfl_up(y, d);
            if (t >= d) y += z;
        }
        wsum[t] = y;
    }
    __syncthreads();
    u32 base = (wv > 0) ? wsum[wv - 1] : 0u;
    u32 incl = base + x;
    hist[(size_t)t * NEXP + e] = incl - v;   // exclusive prefix
    if (t == nchunk - 1) totals[e] = incl;
}

// ---------------- K3: expert base offsets + counts output ----------------
__global__ void k_base(const u32* __restrict__ totals, u32* __restrict__ base,
                       float* __restrict__ out_counts) {
    const int l = threadIdx.x;  // 64
    u32 v = totals[l];
    u32 x = v;
#pragma unroll
    for (int d = 1; d < 64; d <<= 1) {
        u32 y = __shfl_up(x, d);
        if (l >= d) x += y;
    }
    base[l] = x - v;            // exclusive scan
    out_counts[l] = (float)v;
}

// ---------------- K4: stable scatter ----------------
__global__ void k_scatter(const float* __restrict__ scores,
                          const int* __restrict__ experts,
                          const u32* __restrict__ offs,   // == hist (exclusive chunk prefix)
                          const u32* __restrict__ base,
                          float* __restrict__ out_scores,
                          float* __restrict__ out_idx) {
    __shared__ u32 cnt[WPB][NEXP];
    const int tid  = threadIdx.x;
    const int wv   = tid >> 6;
    const int lane = tid & 63;
    const int c = blockIdx.x * WPB + wv;
    cnt[wv][lane] = base[lane] + offs[(size_t)c * NEXP + lane];
    __syncthreads();
#pragma unroll
    for (int r = 0; r < ROUNDS; ++r) {
        const int i = c * CHUNK + r * 64 + lane;
        const int e = experts[i];
        const float s = scores[i];
        // match-any over the 6-bit expert id
        u64 m = ~0ull;
#pragma unroll
        for (int b = 0; b < 6; ++b) {
            u64 bb = __ballot((e >> b) & 1);
            m &= ((e >> b) & 1) ? bb : ~bb;
        }
        const u64 below = m & ((1ull << lane) - 1ull);
        const u32 lower = (u32)__popcll(below);
        const u32 pos = cnt[wv][e] + lower;
        out_scores[pos] = s;
        out_idx[pos]    = (float)(i >> 3);   // i / TOP_K
        if (lower == 0) cnt[wv][e] += (u32)__popcll(m);   // leader updates
        __syncthreads();
    }
}

extern "C" void kernel_launch(void* const* d_in, const int* in_sizes, int n_in,
                              void* d_out, int out_size, void* d_ws, size_t ws_size,
                              hipStream_t stream) {
    const float* top_scores = (const float*)d_in[0];
    const int*   experts    = (const int*)d_in[1];

    const int M = in_sizes[0];            // 1,048,576
    const int nchunk = M / CHUNK;         // 1024
    const int nblocks = nchunk / WPB;     // 256

    u32* hist   = (u32*)d_ws;                       // nchunk*64 u32
    u32* totals = hist + (size_t)nchunk * NEXP;     // 64 u32
    u32* base   = totals + NEXP;                    // 64 u32

    float* out        = (float*)d_out;
    float* out_scores = out;                        // M
    float* out_idx    = out + M;                    // M
    float* out_counts = out + 2 * (size_t)M;        // 64

    k_hist<<<nblocks, 256, 0, stream>>>(experts, hist);
    k_scan_chunks<<<NEXP, nchunk, 0, stream>>>(hist, totals, nchunk);
    k_base<<<1, 64, 0, stream>>>(totals, base, out_counts);
    k_scatter<<<nblocks, 256, 0, stream>>>(top_scores, experts, hist, base,
                                           out_scores, out_idx);
}